// Round 4
// baseline (424.557 us; speedup 1.0000x reference)
//
#include <hip/hip_runtime.h>
#include <hip/hip_bf16.h>

// Problem constants
#define BATCH 32
#define CIN   1024
#define HW    784     // 28*28
#define WIMG  28
#define PADW  30      // padded 30x30 plane
#define PADHW 900
#define P1    256
#define P2    256
#define P3    1024
#define NFLAT (BATCH * HW)   // 25088 = 196 * 128 exactly
#define NT    196            // n-tiles of 128

typedef __attribute__((ext_vector_type(8))) short bfrag_t;          // 8 bf16 (4 VGPRs)
typedef __attribute__((ext_vector_type(8))) unsigned short usvec8;
typedef __attribute__((ext_vector_type(4))) float accvec_t;

static __device__ __forceinline__ unsigned short f2bf(float f) {
    union { __hip_bfloat16 h; unsigned short u; } cv;
    cv.h = __float2bfloat16(f);
    return cv.u;
}
static __device__ __forceinline__ float bf2f(unsigned short u) {
    union { float f; unsigned int i; } cv;
    cv.i = ((unsigned int)u) << 16;
    return cv.f;
}

// async 16B global->LDS DMA. LDS dest is wave-uniform base + lane*16B.
#define GLDS16(g, l) __builtin_amdgcn_global_load_lds(                      \
        (const __attribute__((address_space(1))) void*)(g),                 \
        (__attribute__((address_space(3))) void*)(l), 16, 0, 0)

// ---------------- pre-pass: transpose perm_dconv -> permT[p][c] ----------------
__global__ __launch_bounds__(256) void permT_kernel(const int* __restrict__ perm,
                                                    int* __restrict__ permT) {
    int p = blockIdx.x, c = threadIdx.x;
    permT[p * P1 + c] = perm[c * HW + p];
}

// ---------------- pre-pass: pack weights to bf16 ----------------
__global__ __launch_bounds__(256) void pack_weights_kernel(
        const float* __restrict__ w1, const float* __restrict__ wd,
        const float* __restrict__ w3, unsigned short* __restrict__ w1b,
        unsigned short* __restrict__ wdb, unsigned short* __restrict__ w3b) {
    int i = blockIdx.x * 256 + threadIdx.x;
    if (i < 262144) w1b[i] = f2bf(w1[i]);
    int i2 = i - 262144;
    if (i2 >= 0 && i2 < 262144) w3b[i2] = f2bf(w3[i2]);
    int i3 = i - 524288;
    if (i3 >= 0 && i3 < 589824) {
        int m = i3 / 2304, rem = i3 - m * 2304;
        int k = rem / 9, r = rem - k * 9;
        wdb[((size_t)r * P2 + m) * P1 + k] = f2bf(wd[i3]);
    }
}

// ---------------- fused pre-pass: x -> xt[b*HW+hw][c] AND res[b][c][hw] ----------------
// One read of x; 64-channel plane resident in LDS (stride 790: conflict-free transpose reads).
__global__ __launch_bounds__(512) void prep_x_kernel(const float* __restrict__ x,
                                                     const int* __restrict__ perm_res,
                                                     unsigned short* __restrict__ xt,
                                                     unsigned short* __restrict__ res,
                                                     int write_res) {
    __shared__ unsigned short Ly[64 * 790];   // 101,120 B
    const int b  = blockIdx.x >> 4;
    const int c0 = (blockIdx.x & 15) * 64;
    const int t = threadIdx.x;
    const float* xb = x + ((size_t)(b * CIN + c0)) * HW;
    // load + convert: 64 rows x 196 float4
    for (int chunk = t; chunk < 12544; chunk += 512) {
        int c = chunk / 196, f4 = (chunk - c * 196) * 4;
        float4 v = *(const float4*)&xb[(size_t)c * HW + f4];
        unsigned short* d = &Ly[c * 790 + f4];
        d[0] = f2bf(v.x); d[1] = f2bf(v.y); d[2] = f2bf(v.z); d[3] = f2bf(v.w);
    }
    __syncthreads();
    const int w = t >> 6, j = t & 63;
    // phase A: transpose -> xt (128B coalesced stores; LDS col reads conflict-free)
    unsigned short* xto = xt + ((size_t)b * HW) * CIN + c0 + j;
    const int hw1 = w * 98 + 98;
    for (int hw = w * 98; hw < hw1; ++hw)
        xto[(size_t)hw * CIN] = Ly[j * 790 + hw];
    // phase B: residual shuffle -> res (gather in LDS, coalesced stores)
    if (write_res) {
#pragma unroll
        for (int ci = 0; ci < 8; ++ci) {
            int c = w * 8 + ci;
            const int* pr = perm_res + (size_t)(c0 + c) * HW;
            unsigned short* ro = res + ((size_t)(b * CIN + c0 + c)) * HW;
            for (int q = j; q < HW; q += 64)
                ro[q] = Ly[c * 790 + pr[q]];
        }
    }
}

// ---------------- fallback residual shuffle (reads x again) ----------------
__global__ __launch_bounds__(256) void res_shuffle_kernel(const float* __restrict__ x,
                                                          const int* __restrict__ perm_res,
                                                          unsigned short* __restrict__ res) {
    __shared__ float Lx[8 * 788];
    const int g0 = blockIdx.x * 8;
    const int t = threadIdx.x;
#pragma unroll
    for (int it = 0; it < 7; ++it) {
        int chunk = it * 256 + t;
        if (chunk < 1568) {
            int r = chunk / 196, off = (chunk - r * 196) * 4;
            float4 v = *(const float4*)&x[(size_t)(g0 + r) * HW + off];
            *(float4*)&Lx[r * 788 + off] = v;
        }
    }
    __syncthreads();
    const int q0 = t & 63;
#pragma unroll
    for (int rp = 0; rp < 2; ++rp) {
        int r = rp * 4 + (t >> 6);
        int g = g0 + r;
        int m = g & (CIN - 1);
        const int* pr = perm_res + (size_t)m * HW;
#pragma unroll
        for (int it = 0; it < 13; ++it) {
            int q = it * 64 + q0;
            if (q < HW) res[(size_t)g * HW + q] = f2bf(Lx[r * 788 + pr[q]]);
        }
    }
}

// ---------------- shuffle+pad via LDS (also zeroes borders; replaces memset) ----------------
__global__ __launch_bounds__(256) void shuffle_pad_kernel(const unsigned short* __restrict__ y1c,
                                                          const int* __restrict__ permT,
                                                          unsigned short* __restrict__ y1sp) {
    __shared__ unsigned short Ly[32 * 800];
    const int b  = blockIdx.x >> 3;
    const int c0 = (blockIdx.x & 7) * 32;
    const int t = threadIdx.x;
    unsigned short* ybase = y1sp + (size_t)b * PADHW * P1 + c0;
    // border zeros (independent of LDS; issued first)
    for (int idx = t; idx < 116 * 32; idx += 256) {
        int bp = idx >> 5, c = idx & 31;
        int pos;
        if (bp < 30)      pos = bp;                       // row 0
        else if (bp < 60) pos = 870 + (bp - 30);          // row 29
        else if (bp < 88) pos = (bp - 60 + 1) * 30;       // col 0, rows 1..28
        else              pos = (bp - 88 + 1) * 30 + 29;  // col 29, rows 1..28
        ybase[(size_t)pos * P1 + c] = 0;
    }
    // phase 1: coalesced 16B loads of 32 channel rows
#pragma unroll
    for (int it = 0; it < 13; ++it) {
        int chunk = it * 256 + t;
        if (chunk < 3136) {
            int c = chunk / 98, off8 = (chunk - c * 98) * 8;
            usvec8 v = *(const usvec8*)&y1c[((size_t)(b * P1 + c0 + c)) * HW + off8];
            *(usvec8*)&Ly[c * 800 + off8] = v;
        }
    }
    __syncthreads();
    // phase 2: gather per (pos, channel), 64B channel-segment writes
    const int pc = t & 31, pi = t >> 5;
    unsigned short* yb = ybase + pc;
#pragma unroll 4
    for (int it = 0; it < 98; ++it) {
        int p = it * 8 + pi;
        int pv = permT[p * P1 + c0 + pc];
        unsigned short val = Ly[pc * 800 + pv];
        int ph = p / WIMG, pw = p - ph * WIMG;
        yb[(size_t)((ph + 1) * PADW + pw + 1) * P1] = val;
    }
}

// ======================================================================
// GEMMs: 128x128 tile, 4 waves (2x2), BK=64 with XOR chunk swizzle,
// async global_load_lds (16B). XCD-swizzled 1-D grids: XCD = n_tile % 8.
// ======================================================================

// ---------------- conv1: y1c[b][m][hw] = relu(W1 x X) ----------------
__global__ __launch_bounds__(256) void conv1_kernel(const unsigned short* __restrict__ xt,
                                                    const unsigned short* __restrict__ w1b,
                                                    unsigned short* __restrict__ y1c) {
    const int g = blockIdx.x;
    const int rcls = g & 7, s = g >> 3;          // s < 50
    const int mt = s & 1, q = s >> 1;            // q < 25
    const int nt = q * 8 + rcls;
    if (nt >= NT) return;
    const int m0 = mt * 128, n0 = nt * 128;

    __shared__ __align__(16) unsigned short As[128 * 64];
    __shared__ __align__(16) unsigned short Bs[128 * 64];
    const int t = threadIdx.x;
    const int lane = t & 63, wave = t >> 6;
    const int l15 = lane & 15, quad = lane >> 4;
    const int wm = wave & 1, wn = wave >> 1;
    const int grow = lane >> 3;
    const int gsw  = ((lane & 7) ^ grow) << 3;
    const unsigned short* Asrc[4];
    const unsigned short* Bsrc[4];
    int ldso[4];
#pragma unroll
    for (int j = 0; j < 4; ++j) {
        int qq = wave * 4 + j;
        int row = (qq << 3) + grow;
        Asrc[j] = w1b + (size_t)(m0 + row) * CIN + gsw;
        Bsrc[j] = xt + (size_t)(n0 + row) * CIN + gsw;
        ldso[j] = qq * 512;
    }
    const int coff0 = ((quad)     ^ (l15 & 7)) << 3;
    const int coff1 = ((quad + 4) ^ (l15 & 7)) << 3;

    accvec_t acc[4][4];
    const accvec_t zero = {0.f, 0.f, 0.f, 0.f};
#pragma unroll
    for (int i = 0; i < 4; ++i)
#pragma unroll
        for (int j = 0; j < 4; ++j) acc[i][j] = zero;

    for (int k0 = 0; k0 < CIN; k0 += 64) {
#pragma unroll
        for (int j = 0; j < 4; ++j) {
            GLDS16(Asrc[j] + k0, &As[ldso[j]]);
            GLDS16(Bsrc[j] + k0, &Bs[ldso[j]]);
        }
        __syncthreads();
        bfrag_t af[4], bfr[4];
#pragma unroll
        for (int i = 0; i < 4; ++i) {
            af[i]  = *(const bfrag_t*)&As[(wm * 64 + i * 16 + l15) * 64 + coff0];
            bfr[i] = *(const bfrag_t*)&Bs[(wn * 64 + i * 16 + l15) * 64 + coff0];
        }
#pragma unroll
        for (int im = 0; im < 4; ++im)
#pragma unroll
            for (int in = 0; in < 4; ++in)
                acc[im][in] = __builtin_amdgcn_mfma_f32_16x16x32_bf16(af[im], bfr[in], acc[im][in], 0, 0, 0);
#pragma unroll
        for (int i = 0; i < 4; ++i) {
            af[i]  = *(const bfrag_t*)&As[(wm * 64 + i * 16 + l15) * 64 + coff1];
            bfr[i] = *(const bfrag_t*)&Bs[(wn * 64 + i * 16 + l15) * 64 + coff1];
        }
#pragma unroll
        for (int im = 0; im < 4; ++im)
#pragma unroll
            for (int in = 0; in < 4; ++in)
                acc[im][in] = __builtin_amdgcn_mfma_f32_16x16x32_bf16(af[im], bfr[in], acc[im][in], 0, 0, 0);
        __syncthreads();
    }
#pragma unroll
    for (int in = 0; in < 4; ++in) {
        const int n = n0 + wn * 64 + in * 16 + l15;
        const int b = n / HW, hw = n - b * HW;
#pragma unroll
        for (int im = 0; im < 4; ++im) {
#pragma unroll
            for (int r = 0; r < 4; ++r) {
                const int m = m0 + wm * 64 + im * 16 + (quad << 2) + r;
                float v = acc[im][in][r];
                v = v > 0.f ? v : 0.f;
                y1c[((size_t)(b * P1 + m)) * HW + hw] = f2bf(v);
            }
        }
    }
}

// ---------------- dconv: y2t[n][m] = relu(conv3x3(y1sp, wdb)) ----------------
__global__ __launch_bounds__(256) void dconv_kernel(const unsigned short* __restrict__ y1sp,
                                                    const unsigned short* __restrict__ wdb,
                                                    unsigned short* __restrict__ y2t) {
    const int g = blockIdx.x;
    const int rcls = g & 7, s = g >> 3;
    const int mt = s & 1, q = s >> 1;
    const int nt = q * 8 + rcls;
    if (nt >= NT) return;
    const int m0 = mt * 128, n0 = nt * 128;

    __shared__ __align__(16) unsigned short As[128 * 64];
    __shared__ __align__(16) unsigned short Bs[128 * 64];
    const int t = threadIdx.x;
    const int lane = t & 63, wave = t >> 6;
    const int l15 = lane & 15, quad = lane >> 4;
    const int wm = wave & 1, wn = wave >> 1;
    const int grow = lane >> 3;
    const int gsw  = ((lane & 7) ^ grow) << 3;
    const unsigned short* Asrc[4];
    const unsigned short* Bsrc[4];
    int ldso[4];
#pragma unroll
    for (int j = 0; j < 4; ++j) {
        int qq = wave * 4 + j;
        int row = (qq << 3) + grow;
        Asrc[j] = wdb + (size_t)(m0 + row) * P1 + gsw;
        int n = n0 + row;
        int b = n / HW, hw = n - b * HW;
        int h = hw / WIMG, w = hw - h * WIMG;
        Bsrc[j] = y1sp + ((size_t)b * PADHW + h * PADW + w) * P1 + gsw;
        ldso[j] = qq * 512;
    }
    const int coff0 = ((quad)     ^ (l15 & 7)) << 3;
    const int coff1 = ((quad + 4) ^ (l15 & 7)) << 3;

    accvec_t acc[4][4];
    const accvec_t zero = {0.f, 0.f, 0.f, 0.f};
#pragma unroll
    for (int i = 0; i < 4; ++i)
#pragma unroll
        for (int j = 0; j < 4; ++j) acc[i][j] = zero;

    for (int r = 0; r < 9; ++r) {
        const int kh = r / 3, kw = r - kh * 3;
        const size_t aoff = (size_t)r * (P1 * P2);
        const int taboff = (kh * PADW + kw) * P1;
        for (int k0 = 0; k0 < P1; k0 += 64) {
#pragma unroll
            for (int j = 0; j < 4; ++j) {
                GLDS16(Asrc[j] + aoff + k0, &As[ldso[j]]);
                GLDS16(Bsrc[j] + taboff + k0, &Bs[ldso[j]]);
            }
            __syncthreads();
            bfrag_t af[4], bfr[4];
#pragma unroll
            for (int i = 0; i < 4; ++i) {
                af[i]  = *(const bfrag_t*)&As[(wm * 64 + i * 16 + l15) * 64 + coff0];
                bfr[i] = *(const bfrag_t*)&Bs[(wn * 64 + i * 16 + l15) * 64 + coff0];
            }
#pragma unroll
            for (int im = 0; im < 4; ++im)
#pragma unroll
                for (int in = 0; in < 4; ++in)
                    acc[im][in] = __builtin_amdgcn_mfma_f32_16x16x32_bf16(bfr[in], af[im], acc[im][in], 0, 0, 0);
#pragma unroll
            for (int i = 0; i < 4; ++i) {
                af[i]  = *(const bfrag_t*)&As[(wm * 64 + i * 16 + l15) * 64 + coff1];
                bfr[i] = *(const bfrag_t*)&Bs[(wn * 64 + i * 16 + l15) * 64 + coff1];
            }
#pragma unroll
            for (int im = 0; im < 4; ++im)
#pragma unroll
                for (int in = 0; in < 4; ++in)
                    acc[im][in] = __builtin_amdgcn_mfma_f32_16x16x32_bf16(bfr[in], af[im], acc[im][in], 0, 0, 0);
            __syncthreads();
        }
    }
#pragma unroll
    for (int im = 0; im < 4; ++im) {
        const int m = m0 + wm * 64 + im * 16 + l15;
#pragma unroll
        for (int in = 0; in < 4; ++in) {
#pragma unroll
            for (int r = 0; r < 4; ++r) {
                const int n = n0 + wn * 64 + in * 16 + (quad << 2) + r;
                float v = acc[im][in][r];
                v = v > 0.f ? v : 0.f;
                y2t[(size_t)n * P2 + m] = f2bf(v);
            }
        }
    }
}

// ---------------- conv3 + coalesced residual add + relu (BK=64 structure) ----------------
__global__ __launch_bounds__(256) void conv3_kernel(const unsigned short* __restrict__ y2t,
                                                    const unsigned short* __restrict__ w3b,
                                                    const unsigned short* __restrict__ res,
                                                    float* __restrict__ out) {
    const int g = blockIdx.x;
    const int rcls = g & 7, s = g >> 3;          // s < 200
    const int mt = s & 7, q = s >> 3;            // q < 25
    const int nt = q * 8 + rcls;
    if (nt >= NT) return;
    const int m0 = mt * 128, n0 = nt * 128;

    __shared__ __align__(16) unsigned short As[128 * 64];
    __shared__ __align__(16) unsigned short Bs[128 * 64];
    const int t = threadIdx.x;
    const int lane = t & 63, wave = t >> 6;
    const int l15 = lane & 15, quad = lane >> 4;
    const int wm = wave & 1, wn = wave >> 1;
    const int grow = lane >> 3;
    const int gsw  = ((lane & 7) ^ grow) << 3;
    const unsigned short* Asrc[4];
    const unsigned short* Bsrc[4];
    int ldso[4];
#pragma unroll
    for (int j = 0; j < 4; ++j) {
        int qq = wave * 4 + j;
        int row = (qq << 3) + grow;
        Asrc[j] = w3b + (size_t)(m0 + row) * P2 + gsw;
        Bsrc[j] = y2t + (size_t)(n0 + row) * P2 + gsw;
        ldso[j] = qq * 512;
    }
    const int coff0 = ((quad)     ^ (l15 & 7)) << 3;
    const int coff1 = ((quad + 4) ^ (l15 & 7)) << 3;

    accvec_t acc[4][4];
    const accvec_t zero = {0.f, 0.f, 0.f, 0.f};
#pragma unroll
    for (int i = 0; i < 4; ++i)
#pragma unroll
        for (int j = 0; j < 4; ++j) acc[i][j] = zero;

    for (int k0 = 0; k0 < P2; k0 += 64) {
#pragma unroll
        for (int j = 0; j < 4; ++j) {
            GLDS16(Asrc[j] + k0, &As[ldso[j]]);
            GLDS16(Bsrc[j] + k0, &Bs[ldso[j]]);
        }
        __syncthreads();
        bfrag_t af[4], bfr[4];
#pragma unroll
        for (int i = 0; i < 4; ++i) {
            af[i]  = *(const bfrag_t*)&As[(wm * 64 + i * 16 + l15) * 64 + coff0];
            bfr[i] = *(const bfrag_t*)&Bs[(wn * 64 + i * 16 + l15) * 64 + coff0];
        }
#pragma unroll
        for (int im = 0; im < 4; ++im)
#pragma unroll
            for (int in = 0; in < 4; ++in)
                acc[im][in] = __builtin_amdgcn_mfma_f32_16x16x32_bf16(af[im], bfr[in], acc[im][in], 0, 0, 0);
#pragma unroll
        for (int i = 0; i < 4; ++i) {
            af[i]  = *(const bfrag_t*)&As[(wm * 64 + i * 16 + l15) * 64 + coff1];
            bfr[i] = *(const bfrag_t*)&Bs[(wn * 64 + i * 16 + l15) * 64 + coff1];
        }
#pragma unroll
        for (int im = 0; im < 4; ++im)
#pragma unroll
            for (int in = 0; in < 4; ++in)
                acc[im][in] = __builtin_amdgcn_mfma_f32_16x16x32_bf16(af[im], bfr[in], acc[im][in], 0, 0, 0);
        __syncthreads();
    }
#pragma unroll
    for (int in = 0; in < 4; ++in) {
        const int n = n0 + wn * 64 + in * 16 + l15;
        const int b = n / HW, hw = n - b * HW;
#pragma unroll
        for (int im = 0; im < 4; ++im) {
#pragma unroll
            for (int r = 0; r < 4; ++r) {
                const int m = m0 + wm * 64 + im * 16 + (quad << 2) + r;
                const size_t idx = ((size_t)(b * P3 + m)) * HW + hw;
                float v = acc[im][in][r] + bf2f(res[idx]);
                v = v > 0.f ? v : 0.f;
                out[idx] = v;
            }
        }
    }
}

extern "C" void kernel_launch(void* const* d_in, const int* in_sizes, int n_in,
                              void* d_out, int out_size, void* d_ws, size_t ws_size,
                              hipStream_t stream) {
    const float* x      = (const float*)d_in[0];
    const float* w1     = (const float*)d_in[1];
    const float* wd     = (const float*)d_in[2];
    const float* w3     = (const float*)d_in[3];
    const int*   perm_d = (const int*)d_in[4];
    const int*   perm_r = (const int*)d_in[5];
    float*       out    = (float*)d_out;

    char* ws = (char*)d_ws;
    unsigned short* y1sp  = (unsigned short*)(ws + 0);         // 14,745,600
    unsigned short* y2t   = (unsigned short*)(ws + 14745600);  // 12,845,056 (also y1c)
    int*            permT = (int*)(ws + 27590656);             //    802,816
    unsigned short* w1b   = (unsigned short*)(ws + 28393472);  //    524,288
    unsigned short* wdb   = (unsigned short*)(ws + 28917760);  //  1,179,648
    unsigned short* w3b   = (unsigned short*)(ws + 30097408);  //    524,288
    unsigned short* xt    = (unsigned short*)(ws + 30621696);  // 51,380,224 -> 82,001,920
    unsigned short* y1c   = y2t;
    const size_t FUSED_WS = 82001920ULL + 51380224ULL;         // + res region
    const bool fused = ws_size >= FUSED_WS;
    unsigned short* resb = fused ? (unsigned short*)(ws + 82001920) : xt;

    permT_kernel<<<dim3(HW), dim3(256), 0, stream>>>(perm_d, permT);
    pack_weights_kernel<<<dim3(4352), dim3(256), 0, stream>>>(w1, wd, w3, w1b, wdb, w3b);
    prep_x_kernel<<<dim3(512), dim3(512), 0, stream>>>(x, perm_r, xt, resb, fused ? 1 : 0);

    conv1_kernel<<<dim3(400), dim3(256), 0, stream>>>(xt, w1b, y1c);
    if (!fused)  // res overwrites xt only after conv1 consumed it
        res_shuffle_kernel<<<dim3(BATCH * CIN / 8), dim3(256), 0, stream>>>(x, perm_r, resb);
    shuffle_pad_kernel<<<dim3(BATCH * 8), dim3(256), 0, stream>>>(y1c, permT, y1sp);
    dconv_kernel<<<dim3(400), dim3(256), 0, stream>>>(y1sp, wdb, y2t);
    conv3_kernel<<<dim3(1600), dim3(256), 0, stream>>>(y2t, w3b, resb, out);
}